// Round 1
// baseline (166.044 us; speedup 1.0000x reference)
//
#include <hip/hip_runtime.h>
#include <hip/hip_fp16.h>

#define N_NODES 100000
#define N_EDGES 1600000
#define D_FEAT 64

// 4 feature slices of 16 fp16 feats (32B/row). One plane = 3.2MB -> fits a
// single XCD's 4MB L2. Slice pinned to XCD via q = blockIdx.x & 3 (round-robin
// b%8 dispatch => XCD x only touches plane x%4).
#define SLICES 4

typedef __attribute__((ext_vector_type(4))) _Float16 half4v;
typedef __attribute__((ext_vector_type(4))) float    f32x4;

// ---------------------------------------------------------------------------
// Prep (fused): part A converts x (fp32) -> xh sliced planes [4][N][16] fp16;
//               part B builds CSR row_ptr from sorted target_index.
// ---------------------------------------------------------------------------
__global__ __launch_bounds__(256) void prep_kernel(
    const f32x4* __restrict__ x4,    // [N_NODES*16]
    const int*   __restrict__ tgt,   // [N_EDGES] sorted
    half4v*      __restrict__ xh4,   // [4][N_NODES][4] half4 (= [4][N][16] fp16)
    int*         __restrict__ row_ptr,
    int conv_blocks)
{
    const int bid = blockIdx.x;
    if (bid < conv_blocks) {
        int i = bid * 256 + threadIdx.x;       // one float4 -> one half4
        if (i < N_NODES * 16) {
            f32x4 v = __builtin_nontemporal_load(&x4[i]);
            half4v h;
            h.x = (_Float16)v.x; h.y = (_Float16)v.y;
            h.z = (_Float16)v.z; h.w = (_Float16)v.w;
            int n = i >> 4;            // node
            int g = i & 15;            // which float4 of the row (feats 4g..4g+3)
            int q = g >> 2;            // slice 0..3
            int slot = g & 3;          // half4 slot within slice
            // plane-major: ((q*N + n) * 4 + slot)
            __builtin_nontemporal_store(h, &xh4[(((q * N_NODES) + n) << 2) | slot]);
        }
    } else {
        int e = (bid - conv_blocks) * 256 + threadIdx.x;
        if (e >= N_EDGES) return;
        int cur = tgt[e];
        int lo  = (e == 0) ? 0 : tgt[e - 1] + 1;
        for (int n = lo; n <= cur; ++n) row_ptr[n] = e;
        if (e == N_EDGES - 1) {
            for (int n = cur + 1; n <= N_NODES; ++n) row_ptr[n] = N_EDGES;
        }
    }
}

// Standalone row_ptr build (fallback path)
__global__ __launch_bounds__(256) void build_row_ptr(
    const int* __restrict__ tgt, int* __restrict__ row_ptr)
{
    int e = blockIdx.x * blockDim.x + threadIdx.x;
    if (e >= N_EDGES) return;
    int cur = tgt[e];
    int lo  = (e == 0) ? 0 : tgt[e - 1] + 1;
    for (int n = lo; n <= cur; ++n) row_ptr[n] = e;
    if (e == N_EDGES - 1) {
        for (int n = cur + 1; n <= N_NODES; ++n) row_ptr[n] = N_EDGES;
    }
}

// ---------------------------------------------------------------------------
// Sliced gather-sum: block handles ONE slice q (pinned per-XCD) x 16 nodes.
// 16-lane group owns one node end-to-end; per edge each lane reads ONE fp16
// feat (2B d16 load, group request = 32B from the L2-resident plane).
// Meta (src,ev) staged via LDS (group-uniform b128 broadcasts), 2-deep chunk
// pipeline, nontemporal on streaming meta/out to protect L2 residency.
// ---------------------------------------------------------------------------
#define GROUPS_PER_BLOCK 16
#define LDS_STRIDE_B     144   // 16 slots * 8B + 16B pad

__global__ __launch_bounds__(256) void gather_sum_slice(
    const _Float16* __restrict__ xh,      // [4][N_NODES][16] fp16
    const float*    __restrict__ ev,
    const int*      __restrict__ src,
    const int*      __restrict__ row_ptr,
    float*          __restrict__ out)     // [N_NODES, 64] fp32
{
    __shared__ char lds_raw[GROUPS_PER_BLOCK * LDS_STRIDE_B];

    const int tib  = threadIdx.x;
    const int gib  = tib >> 4;          // group within block: 0..15
    const int lane = tib & 15;          // lane within group (= feat within slice)
    const int q    = blockIdx.x & 3;    // slice, constant per XCD under b%8 rr
    const int node = (blockIdx.x >> 2) * GROUPS_PER_BLOCK + gib;
    if (node >= N_NODES) return;

    const _Float16* __restrict__ xq = xh + (size_t)q * (N_NODES * 16);

    char* gbase = lds_raw + gib * LDS_STRIDE_B;

    const int start = row_ptr[node];
    const int end   = row_ptr[node + 1];

    float acc = 0.0f;

    for (int blk = start; blk < end; blk += 16) {
        const int bcnt = end - blk;          // >=1; clamp handled by padding

        // stage this block's (src, ev) pairs; pad unused slots with (0, 0.0f)
        int   s_ = 0; float w_ = 0.0f;
        if (lane < bcnt) {
            s_ = __builtin_nontemporal_load(&src[blk + lane]);
            w_ = __builtin_nontemporal_load(&ev[blk + lane]);
        }
        ((int2*)gbase)[lane] = make_int2(s_, __float_as_int(w_));

        const int nch = (min(bcnt, 16) + 3) >> 2;   // chunks of 4 edges

        // ---- chunk 0: meta broadcast + 4 gathers (2B each, 32B/group/edge)
        int4 m01 = ((const int4*)gbase)[0];   // s0,w0,s1,w1
        int4 m23 = ((const int4*)gbase)[1];   // s2,w2,s3,w3
        _Float16 x0 = xq[(m01.x << 4) + lane];
        _Float16 x1 = xq[(m01.z << 4) + lane];
        _Float16 x2 = xq[(m23.x << 4) + lane];
        _Float16 x3 = xq[(m23.z << 4) + lane];
        float w0 = __int_as_float(m01.y), w1 = __int_as_float(m01.w);
        float w2 = __int_as_float(m23.y), w3 = __int_as_float(m23.w);

        for (int c = 1; c < nch; ++c) {
            // next chunk: meta + gathers issued before consuming current
            int4 n01 = ((const int4*)gbase)[2 * c];
            int4 n23 = ((const int4*)gbase)[2 * c + 1];
            _Float16 nx0 = xq[(n01.x << 4) + lane];
            _Float16 nx1 = xq[(n01.z << 4) + lane];
            _Float16 nx2 = xq[(n23.x << 4) + lane];
            _Float16 nx3 = xq[(n23.z << 4) + lane];

            // consume current chunk
            acc = fmaf(w0, (float)x0, acc);
            acc = fmaf(w1, (float)x1, acc);
            acc = fmaf(w2, (float)x2, acc);
            acc = fmaf(w3, (float)x3, acc);

            x0 = nx0; x1 = nx1; x2 = nx2; x3 = nx3;
            w0 = __int_as_float(n01.y); w1 = __int_as_float(n01.w);
            w2 = __int_as_float(n23.y); w3 = __int_as_float(n23.w);
        }

        // consume final chunk
        acc = fmaf(w0, (float)x0, acc);
        acc = fmaf(w1, (float)x1, acc);
        acc = fmaf(w2, (float)x2, acc);
        acc = fmaf(w3, (float)x3, acc);
    }

    // out[node][q*16 + lane]; 16 lanes = 64B coalesced, NT to spare L2
    __builtin_nontemporal_store(acc, &out[(size_t)node * 64 + (q << 4) + lane]);
}

// fp32 fallback gather (R3 structure) if ws can't hold xh
__global__ __launch_bounds__(256) void gather_sum_f32(
    const float4* __restrict__ x4,
    const float*  __restrict__ ev,
    const int*    __restrict__ src,
    const int*    __restrict__ row_ptr,
    float4*       __restrict__ out4)
{
    const int node = blockIdx.x * 4 + (threadIdx.x >> 6);
    if (node >= N_NODES) return;
    const int lane = threadIdx.x & 63;
    const int g    = lane >> 4;
    const int f    = lane & 15;

    const int start = row_ptr[node];
    const int end   = row_ptr[node + 1];

    float4 acc = make_float4(0.f, 0.f, 0.f, 0.f);
    if (start < end) {
        int  ea = start + g, eb = start + 4 + g;
        bool va = ea < end,  vb = eb < end;
        int  esa = va ? ea : start, esb = vb ? eb : start;
        float wa = va ? ev[esa] : 0.0f;
        float wb = vb ? ev[esb] : 0.0f;
        int   sa = src[esa];
        int   sb = src[esb];

        for (int e0 = start; e0 < end; e0 += 8) {
            const float4 xa = x4[sa * 16 + f];
            const float4 xb = x4[sb * 16 + f];
            const float cwa = wa, cwb = wb;
            {
                int  na = e0 + 8 + g, nb = e0 + 12 + g;
                bool vna = na < end,  vnb = nb < end;
                int  nsa = vna ? na : start, nsb = vnb ? nb : start;
                wa = vna ? ev[nsa] : 0.0f;
                wb = vnb ? ev[nsb] : 0.0f;
                sa = src[nsa];
                sb = src[nsb];
            }
            acc.x = fmaf(cwa, xa.x, acc.x);
            acc.y = fmaf(cwa, xa.y, acc.y);
            acc.z = fmaf(cwa, xa.z, acc.z);
            acc.w = fmaf(cwa, xa.w, acc.w);
            acc.x = fmaf(cwb, xb.x, acc.x);
            acc.y = fmaf(cwb, xb.y, acc.y);
            acc.z = fmaf(cwb, xb.z, acc.z);
            acc.w = fmaf(cwb, xb.w, acc.w);
        }
    }
    acc.x += __shfl_xor(acc.x, 16, 64);
    acc.y += __shfl_xor(acc.y, 16, 64);
    acc.z += __shfl_xor(acc.z, 16, 64);
    acc.w += __shfl_xor(acc.w, 16, 64);
    acc.x += __shfl_xor(acc.x, 32, 64);
    acc.y += __shfl_xor(acc.y, 32, 64);
    acc.z += __shfl_xor(acc.z, 32, 64);
    acc.w += __shfl_xor(acc.w, 32, 64);
    if (g == 0) out4[node * 16 + f] = acc;
}

extern "C" void kernel_launch(void* const* d_in, const int* in_sizes, int n_in,
                              void* d_out, int out_size, void* d_ws, size_t ws_size,
                              hipStream_t stream) {
    const float* x            = (const float*)d_in[0];
    const float* edge_values  = (const float*)d_in[1];
    const int*   target_index = (const int*)d_in[2];
    const int*   source_index = (const int*)d_in[3];
    float*       out          = (float*)d_out;

    const size_t rp_bytes = (size_t)(N_NODES + 1) * sizeof(int);
    const size_t xh_off   = (rp_bytes + 511) & ~(size_t)511;
    const size_t xh_bytes = (size_t)N_NODES * D_FEAT * sizeof(_Float16); // 12.8 MB
    const size_t need     = xh_off + xh_bytes;

    int* row_ptr = (int*)d_ws;

    if (ws_size >= need) {
        _Float16* xh = (_Float16*)((char*)d_ws + xh_off);
        const int conv_blocks = (N_NODES * 16 + 255) / 256;          // 6250
        const int rp_blocks   = (N_EDGES + 255) / 256;               // 6250
        prep_kernel<<<conv_blocks + rp_blocks, 256, 0, stream>>>(
            (const f32x4*)x, target_index, (half4v*)xh, row_ptr, conv_blocks);

        // SLICES * 6250 = 25000 blocks (divisible by 8 -> clean XCD pinning)
        const int n_blocks = SLICES * ((N_NODES + GROUPS_PER_BLOCK - 1) / GROUPS_PER_BLOCK);
        gather_sum_slice<<<n_blocks, 256, 0, stream>>>(
            xh, edge_values, source_index, row_ptr, out);
    } else {
        build_row_ptr<<<(N_EDGES + 255) / 256, 256, 0, stream>>>(target_index, row_ptr);
        gather_sum_f32<<<(N_NODES + 3) / 4, 256, 0, stream>>>(
            (const float4*)x, edge_values, source_index, row_ptr, (float4*)out);
    }
}

// Round 2
// 121.345 us; speedup vs baseline: 1.3684x; 1.3684x over previous
//
#include <hip/hip_runtime.h>
#include <hip/hip_fp16.h>

#define N_NODES 100000
#define N_EDGES 1600000
#define D_FEAT 64

typedef __attribute__((ext_vector_type(4))) _Float16 half4v;
typedef __attribute__((ext_vector_type(8))) _Float16 half8v;

// ---------------------------------------------------------------------------
// Prep (fused): part A converts x (fp32) -> xh (fp16, 128B rows);
//               part B builds CSR row_ptr from sorted target_index.
// (round-0 structure: linear [N][64] fp16 layout, no slicing, no NT)
// ---------------------------------------------------------------------------
__global__ __launch_bounds__(256) void prep_kernel(
    const float4* __restrict__ x4,   // [N_NODES*16]
    const int*    __restrict__ tgt,  // [N_EDGES] sorted
    half4v*       __restrict__ xh,   // [N_NODES*16]
    int*          __restrict__ row_ptr,
    int conv_blocks)
{
    const int bid = blockIdx.x;
    if (bid < conv_blocks) {
        int i = bid * 256 + threadIdx.x;       // one float4 -> one half4
        if (i < N_NODES * 16) {
            float4 v = x4[i];
            half4v h;
            h.x = (_Float16)v.x; h.y = (_Float16)v.y;
            h.z = (_Float16)v.z; h.w = (_Float16)v.w;
            xh[i] = h;
        }
    } else {
        int e = (bid - conv_blocks) * 256 + threadIdx.x;
        if (e >= N_EDGES) return;
        int cur = tgt[e];
        int lo  = (e == 0) ? 0 : tgt[e - 1] + 1;
        for (int n = lo; n <= cur; ++n) row_ptr[n] = e;
        if (e == N_EDGES - 1) {
            for (int n = cur + 1; n <= N_NODES; ++n) row_ptr[n] = N_EDGES;
        }
    }
}

// Standalone row_ptr build (fallback path)
__global__ __launch_bounds__(256) void build_row_ptr(
    const int* __restrict__ tgt, int* __restrict__ row_ptr)
{
    int e = blockIdx.x * blockDim.x + threadIdx.x;
    if (e >= N_EDGES) return;
    int cur = tgt[e];
    int lo  = (e == 0) ? 0 : tgt[e - 1] + 1;
    for (int n = lo; n <= cur; ++n) row_ptr[n] = e;
    if (e == N_EDGES - 1) {
        for (int n = cur + 1; n <= N_NODES; ++n) row_ptr[n] = N_EDGES;
    }
}

// ---------------------------------------------------------------------------
// Gather-sum over fp16 rows: one 8-lane group owns one node end-to-end.
// Each lane reads 16B (half8) per edge -> 8 lanes cover the 128B row in ONE
// cacheline request (1 request/edge, the minimum). A 64-lane wave = 8 groups
// = 8 rows per gather instruction (2x fewer instrs than the 16-lane variant).
// Per 16-edge block: meta staged via one ds_write_b128/lane (lane l writes
// edge pairs 2l,2l+1), chunk loop reads group-uniform int4 broadcasts,
// 2-deep pipeline = 8 rows in flight per group (64 per wave).
// Slots past the node's degree are padded s=0,w=0 (harmless row-0 loads).
// ---------------------------------------------------------------------------
#define GROUPS_PER_BLOCK 32          // 8 lanes per group, 256 threads
#define LDS_STRIDE_B     144         // 16 slots * 8B + 16B pad (16B-aligned)

__global__ __launch_bounds__(256) void gather_sum_h(
    const half8v* __restrict__ xh8,      // [N_NODES, 8] half8 (=[N][64] fp16)
    const float*  __restrict__ ev,
    const int*    __restrict__ src,
    const int*    __restrict__ row_ptr,
    float4*       __restrict__ out4)     // [N_NODES, 16] float4
{
    __shared__ char lds_raw[GROUPS_PER_BLOCK * LDS_STRIDE_B];

    const int tib  = threadIdx.x;
    const int gib  = tib >> 3;          // group within block: 0..31
    const int lane = tib & 7;           // lane within group (feats 8*lane..)
    const int node = blockIdx.x * GROUPS_PER_BLOCK + gib;
    if (node >= N_NODES) return;

    char* gbase = lds_raw + gib * LDS_STRIDE_B;

    const int start = row_ptr[node];
    const int end   = row_ptr[node + 1];

    float acc0 = 0.f, acc1 = 0.f, acc2 = 0.f, acc3 = 0.f;
    float acc4 = 0.f, acc5 = 0.f, acc6 = 0.f, acc7 = 0.f;

    for (int blk = start; blk < end; blk += 16) {
        const int bcnt = end - blk;          // >=1; clamp handled by padding

        // stage this block's (src, ev) pairs; lane l stages edges 2l, 2l+1
        int   sa = 0, sb = 0; float wa = 0.0f, wb = 0.0f;
        int ea = blk + 2 * lane, eb = ea + 1;
        if (2 * lane     < bcnt) { sa = src[ea]; wa = ev[ea]; }
        if (2 * lane + 1 < bcnt) { sb = src[eb]; wb = ev[eb]; }
        ((int4*)gbase)[lane] = make_int4(sa, __float_as_int(wa),
                                         sb, __float_as_int(wb));

        const int nch = (min(bcnt, 16) + 3) >> 2;   // chunks of 4 edges

        // ---- chunk 0: meta broadcast + 4 gathers (16B/lane, 128B/row req)
        int4 m01 = ((const int4*)gbase)[0];   // s0,w0,s1,w1
        int4 m23 = ((const int4*)gbase)[1];   // s2,w2,s3,w3
        half8v x0 = xh8[m01.x * 8 + lane];
        half8v x1 = xh8[m01.z * 8 + lane];
        half8v x2 = xh8[m23.x * 8 + lane];
        half8v x3 = xh8[m23.z * 8 + lane];
        float w0 = __int_as_float(m01.y), w1 = __int_as_float(m01.w);
        float w2 = __int_as_float(m23.y), w3 = __int_as_float(m23.w);

        for (int c = 1; c < nch; ++c) {
            // next chunk: meta + gathers issued before consuming current
            int4 n01 = ((const int4*)gbase)[2 * c];
            int4 n23 = ((const int4*)gbase)[2 * c + 1];
            half8v nx0 = xh8[n01.x * 8 + lane];
            half8v nx1 = xh8[n01.z * 8 + lane];
            half8v nx2 = xh8[n23.x * 8 + lane];
            half8v nx3 = xh8[n23.z * 8 + lane];

            // consume current chunk (edge order preserved: e0,e1,e2,e3)
            acc0 = fmaf(w0, (float)x0[0], acc0);
            acc1 = fmaf(w0, (float)x0[1], acc1);
            acc2 = fmaf(w0, (float)x0[2], acc2);
            acc3 = fmaf(w0, (float)x0[3], acc3);
            acc4 = fmaf(w0, (float)x0[4], acc4);
            acc5 = fmaf(w0, (float)x0[5], acc5);
            acc6 = fmaf(w0, (float)x0[6], acc6);
            acc7 = fmaf(w0, (float)x0[7], acc7);
            acc0 = fmaf(w1, (float)x1[0], acc0);
            acc1 = fmaf(w1, (float)x1[1], acc1);
            acc2 = fmaf(w1, (float)x1[2], acc2);
            acc3 = fmaf(w1, (float)x1[3], acc3);
            acc4 = fmaf(w1, (float)x1[4], acc4);
            acc5 = fmaf(w1, (float)x1[5], acc5);
            acc6 = fmaf(w1, (float)x1[6], acc6);
            acc7 = fmaf(w1, (float)x1[7], acc7);
            acc0 = fmaf(w2, (float)x2[0], acc0);
            acc1 = fmaf(w2, (float)x2[1], acc1);
            acc2 = fmaf(w2, (float)x2[2], acc2);
            acc3 = fmaf(w2, (float)x2[3], acc3);
            acc4 = fmaf(w2, (float)x2[4], acc4);
            acc5 = fmaf(w2, (float)x2[5], acc5);
            acc6 = fmaf(w2, (float)x2[6], acc6);
            acc7 = fmaf(w2, (float)x2[7], acc7);
            acc0 = fmaf(w3, (float)x3[0], acc0);
            acc1 = fmaf(w3, (float)x3[1], acc1);
            acc2 = fmaf(w3, (float)x3[2], acc2);
            acc3 = fmaf(w3, (float)x3[3], acc3);
            acc4 = fmaf(w3, (float)x3[4], acc4);
            acc5 = fmaf(w3, (float)x3[5], acc5);
            acc6 = fmaf(w3, (float)x3[6], acc6);
            acc7 = fmaf(w3, (float)x3[7], acc7);

            x0 = nx0; x1 = nx1; x2 = nx2; x3 = nx3;
            w0 = __int_as_float(n01.y); w1 = __int_as_float(n01.w);
            w2 = __int_as_float(n23.y); w3 = __int_as_float(n23.w);
        }

        // consume final chunk
        acc0 = fmaf(w0, (float)x0[0], acc0);
        acc1 = fmaf(w0, (float)x0[1], acc1);
        acc2 = fmaf(w0, (float)x0[2], acc2);
        acc3 = fmaf(w0, (float)x0[3], acc3);
        acc4 = fmaf(w0, (float)x0[4], acc4);
        acc5 = fmaf(w0, (float)x0[5], acc5);
        acc6 = fmaf(w0, (float)x0[6], acc6);
        acc7 = fmaf(w0, (float)x0[7], acc7);
        acc0 = fmaf(w1, (float)x1[0], acc0);
        acc1 = fmaf(w1, (float)x1[1], acc1);
        acc2 = fmaf(w1, (float)x1[2], acc2);
        acc3 = fmaf(w1, (float)x1[3], acc3);
        acc4 = fmaf(w1, (float)x1[4], acc4);
        acc5 = fmaf(w1, (float)x1[5], acc5);
        acc6 = fmaf(w1, (float)x1[6], acc6);
        acc7 = fmaf(w1, (float)x1[7], acc7);
        acc0 = fmaf(w2, (float)x2[0], acc0);
        acc1 = fmaf(w2, (float)x2[1], acc1);
        acc2 = fmaf(w2, (float)x2[2], acc2);
        acc3 = fmaf(w2, (float)x2[3], acc3);
        acc4 = fmaf(w2, (float)x2[4], acc4);
        acc5 = fmaf(w2, (float)x2[5], acc5);
        acc6 = fmaf(w2, (float)x2[6], acc6);
        acc7 = fmaf(w2, (float)x2[7], acc7);
        acc0 = fmaf(w3, (float)x3[0], acc0);
        acc1 = fmaf(w3, (float)x3[1], acc1);
        acc2 = fmaf(w3, (float)x3[2], acc2);
        acc3 = fmaf(w3, (float)x3[3], acc3);
        acc4 = fmaf(w3, (float)x3[4], acc4);
        acc5 = fmaf(w3, (float)x3[5], acc5);
        acc6 = fmaf(w3, (float)x3[6], acc6);
        acc7 = fmaf(w3, (float)x3[7], acc7);
    }

    // out[node][8*lane .. 8*lane+7]: two float4 stores, 256B/group coalesced
    out4[node * 16 + 2 * lane]     = make_float4(acc0, acc1, acc2, acc3);
    out4[node * 16 + 2 * lane + 1] = make_float4(acc4, acc5, acc6, acc7);
}

// fp32 fallback gather (R3 structure) if ws can't hold xh
__global__ __launch_bounds__(256) void gather_sum_f32(
    const float4* __restrict__ x4,
    const float*  __restrict__ ev,
    const int*    __restrict__ src,
    const int*    __restrict__ row_ptr,
    float4*       __restrict__ out4)
{
    const int node = blockIdx.x * 4 + (threadIdx.x >> 6);
    if (node >= N_NODES) return;
    const int lane = threadIdx.x & 63;
    const int g    = lane >> 4;
    const int f    = lane & 15;

    const int start = row_ptr[node];
    const int end   = row_ptr[node + 1];

    float4 acc = make_float4(0.f, 0.f, 0.f, 0.f);
    if (start < end) {
        int  ea = start + g, eb = start + 4 + g;
        bool va = ea < end,  vb = eb < end;
        int  esa = va ? ea : start, esb = vb ? eb : start;
        float wa = va ? ev[esa] : 0.0f;
        float wb = vb ? ev[esb] : 0.0f;
        int   sa = src[esa];
        int   sb = src[esb];

        for (int e0 = start; e0 < end; e0 += 8) {
            const float4 xa = x4[sa * 16 + f];
            const float4 xb = x4[sb * 16 + f];
            const float cwa = wa, cwb = wb;
            {
                int  na = e0 + 8 + g, nb = e0 + 12 + g;
                bool vna = na < end,  vnb = nb < end;
                int  nsa = vna ? na : start, nsb = vnb ? nb : start;
                wa = vna ? ev[nsa] : 0.0f;
                wb = vnb ? ev[nsb] : 0.0f;
                sa = src[nsa];
                sb = src[nsb];
            }
            acc.x = fmaf(cwa, xa.x, acc.x);
            acc.y = fmaf(cwa, xa.y, acc.y);
            acc.z = fmaf(cwa, xa.z, acc.z);
            acc.w = fmaf(cwa, xa.w, acc.w);
            acc.x = fmaf(cwb, xb.x, acc.x);
            acc.y = fmaf(cwb, xb.y, acc.y);
            acc.z = fmaf(cwb, xb.z, acc.z);
            acc.w = fmaf(cwb, xb.w, acc.w);
        }
    }
    acc.x += __shfl_xor(acc.x, 16, 64);
    acc.y += __shfl_xor(acc.y, 16, 64);
    acc.z += __shfl_xor(acc.z, 16, 64);
    acc.w += __shfl_xor(acc.w, 16, 64);
    acc.x += __shfl_xor(acc.x, 32, 64);
    acc.y += __shfl_xor(acc.y, 32, 64);
    acc.z += __shfl_xor(acc.z, 32, 64);
    acc.w += __shfl_xor(acc.w, 32, 64);
    if (g == 0) out4[node * 16 + f] = acc;
}

extern "C" void kernel_launch(void* const* d_in, const int* in_sizes, int n_in,
                              void* d_out, int out_size, void* d_ws, size_t ws_size,
                              hipStream_t stream) {
    const float* x            = (const float*)d_in[0];
    const float* edge_values  = (const float*)d_in[1];
    const int*   target_index = (const int*)d_in[2];
    const int*   source_index = (const int*)d_in[3];
    float*       out          = (float*)d_out;

    const size_t rp_bytes = (size_t)(N_NODES + 1) * sizeof(int);
    const size_t xh_off   = (rp_bytes + 511) & ~(size_t)511;
    const size_t xh_bytes = (size_t)N_NODES * D_FEAT * sizeof(_Float16); // 12.8 MB
    const size_t need     = xh_off + xh_bytes;

    int* row_ptr = (int*)d_ws;

    if (ws_size >= need) {
        half4v* xh = (half4v*)((char*)d_ws + xh_off);
        const int conv_blocks = (N_NODES * 16 + 255) / 256;          // 6250
        const int rp_blocks   = (N_EDGES + 255) / 256;               // 6250
        prep_kernel<<<conv_blocks + rp_blocks, 256, 0, stream>>>(
            (const float4*)x, target_index, xh, row_ptr, conv_blocks);

        const int n_blocks = (N_NODES + GROUPS_PER_BLOCK - 1) / GROUPS_PER_BLOCK;
        gather_sum_h<<<n_blocks, 256, 0, stream>>>(
            (const half8v*)xh, edge_values, source_index, row_ptr, (float4*)out);
    } else {
        build_row_ptr<<<(N_EDGES + 255) / 256, 256, 0, stream>>>(target_index, row_ptr);
        gather_sum_f32<<<(N_NODES + 3) / 4, 256, 0, stream>>>(
            (const float4*)x, edge_values, source_index, row_ptr, (float4*)out);
    }
}